// Round 6
// baseline (1663.689 us; speedup 1.0000x reference)
//
#include <hip/hip_runtime.h>
#include <hip/hip_bf16.h>

// TextRelationalGraphAttention on MI355X.
// Sizes: N=4096, D=O=256, 2H=512, T=512, S=8, R=4, BN=2.
// Float input dtype (f32 vs bf16) detected at runtime from ln_gamma (= ones):
// first u32 word is 0x3F803F80 (bf16) vs 0x3F800000 (f32).
//
// Math: s1 cancels in softmax over j (W_1/graph_guids_1 dead);
// fused[r,i,:] = (M_r @ (e2_r*EW_r)) / (M_r @ e2_r); basis W folded into EW.
//
// R9 = MEASUREMENT round (all kernels < 158us fill-visibility floor; model
// under-explains 521us by >100us):
//  - k_big and k_fplus bodies wrapped in rep<2 loops (idempotent: identical
//    values rewritten; acc reset per rep; all indexing still static). If true
//    dur X > 79us the doubled dispatch crosses the 158us visibility floor and
//    surfaces its OWN counters (FETCH/MfmaUtil/hbm) in the top-5 table.
//    dur delta vs R8 cross-checks X_big + X_fplus.
//  - bundled safe win: k_ctx + k_g2 merged into k_cg (8 blocks; per-block
//    redundant softmax from scores ws; ALL summation orders preserved ->
//    bitwise-identical g2). One launch + one gap removed.
//  - everything else identical to R8 (best: 521.4us).

typedef unsigned short u16;
typedef short bf16x8 __attribute__((ext_vector_type(8)));   // 8 bf16 = 4 VGPRs (MFMA A/B frag)
typedef float f32x4 __attribute__((ext_vector_type(4)));    // MFMA C/D frag
typedef float f32x8 __attribute__((ext_vector_type(8)));
typedef int   v4i   __attribute__((ext_vector_type(4)));    // 16B load/store
typedef unsigned int v2u __attribute__((ext_vector_type(2)));

// ws layout (bytes)
#define G2_OFF    0          // [4][256] f32
#define SC_OFF    4096       // scores [512 t][4 r] f32
#define WRT_OFF   69632      // [4][256 c][256 d] bf16
#define FPT_OFF   593920     // [4][128 kt][272 c][32 kk] bf16 (c=256 row = e2, 257..271 = 0)
#define FUSED_OFF 9506816    // [4][4096 i][256 c] f32
#define CAN_OFF   26284032   // canonical bf16 entity [4096*256]

__device__ __forceinline__ float b2f(u16 u) {
    union { unsigned int i; float f; } v; v.i = ((unsigned int)u) << 16; return v.f;
}
__device__ __forceinline__ u16 f2b(float f) {  // RNE, finite inputs only
    union { float f; unsigned int i; } v; v.f = f;
    return (u16)((v.i + 0x7FFFu + ((v.i >> 16) & 1u)) >> 16);
}
__device__ __forceinline__ float rawf(const void* p, bool isbf, int i) {
    return isbf ? b2f(((const u16*)p)[i]) : ((const float*)p)[i];
}
__device__ __forceinline__ f32x8 raw8(const void* p, bool isbf, int i8) {  // i8 % 8 == 0
    f32x8 o;
    if (isbf) {
        bf16x8 v = *(const bf16x8*)((const u16*)p + i8);
        #pragma unroll
        for (int k = 0; k < 8; ++k) o[k] = b2f((u16)v[k]);
    } else {
        const float* f = (const float*)p + i8;
        float4 a = *(const float4*)f, b = *(const float4*)(f + 4);
        o[0] = a.x; o[1] = a.y; o[2] = a.z; o[3] = a.w;
        o[4] = b.x; o[5] = b.y; o[6] = b.z; o[7] = b.w;
    }
    return o;
}

// ---------------- K1 (k_front): entity-cvt + WrT + scores, one launch --------------------
// blocks 0..255: entity cvt. 256..383: wrt. 384..415: scores (16 t-rows each).
__global__ __launch_bounds__(512) void k_front(
    const void* __restrict__ ent_raw, const void* __restrict__ te_raw,
    const int* __restrict__ adj, const void* __restrict__ tg_raw,
    const void* __restrict__ bV_raw, const void* __restrict__ bb_raw,
    const unsigned* __restrict__ graw,
    u16* __restrict__ ent_can, float* __restrict__ sc_ws, u16* __restrict__ wrt)
{
    bool isbf = (graw[0] == 0x3F803F80u);
    int b = blockIdx.x, tid = threadIdx.x;
    if (b < 256) {               // ---- entity canonicalize: 256 blk x 512 thr x 8 elems
        int base = b * 4096 + tid;
        if (isbf) {
            const u16* s = (const u16*)ent_raw;
            #pragma unroll
            for (int k = 0; k < 8; ++k) { int i = base + k * 512; ent_can[i] = s[i]; }
        } else {
            const float* s = (const float*)ent_raw;
            #pragma unroll
            for (int k = 0; k < 8; ++k) { int i = base + k * 512; ent_can[i] = f2b(s[i]); }
        }
        return;
    }
    if (b < 384) {               // ---- WrT[r][c][d] = sum_b bb[adj[d%4],b] * bV[64r+d/4,b,c]
        int b2 = b - 256;
        int r = b2 >> 5, cq = b2 & 31;
        int c = cq * 8 + (tid >> 6);
        int dq = tid & 63;       // d/4
        int a[4] = {adj[0], adj[1], adj[2], adj[3]};
        #pragma unroll
        for (int dd = 0; dd < 4; ++dd) {
            float w = 0.f;
            #pragma unroll
            for (int bi = 0; bi < 2; ++bi)
                w += rawf(bb_raw, isbf, a[dd] * 2 + bi) *
                     rawf(bV_raw, isbf, ((64 * r + dq) * 2 + bi) * 256 + c);
            wrt[(r * 256 + c) * 256 + dq * 4 + dd] = f2b(w);
        }
        return;
    }
    // ---- scores[t][r] = te[t,:] . tg[r,:], 32 blocks x 16 t-rows
    __shared__ float s_tg[4 * 512];
    int a[4] = {adj[0], adj[1], adj[2], adj[3]};
    for (int idx = tid; idx < 2048; idx += 512) {
        int r = idx >> 9, h = idx & 511;
        s_tg[r * 512 + h] = rawf(tg_raw, isbf, a[r] * 512 + h);
    }
    __syncthreads();
    int b2 = b - 384;
    int t = b2 * 16 + (tid >> 5);      // 16 t per block, 32 lanes per t
    int h0 = (tid & 31) * 16;          // each lane: 16 h's
    float s[4] = {0.f, 0.f, 0.f, 0.f};
    #pragma unroll
    for (int half = 0; half < 2; ++half) {
        f32x8 v = raw8(te_raw, isbf, t * 512 + h0 + half * 8);
        #pragma unroll
        for (int k = 0; k < 8; ++k) {
            float tv = v[k]; int h = h0 + half * 8 + k;
            #pragma unroll
            for (int r = 0; r < 4; ++r) s[r] += tv * s_tg[r * 512 + h];
        }
    }
    #pragma unroll
    for (int r = 0; r < 4; ++r) {      // reduce across the 32-lane h-split
        #pragma unroll
        for (int m = 16; m > 0; m >>= 1) s[r] += __shfl_xor(s[r], m);
    }
    if ((tid & 31) == 0) {
        #pragma unroll
        for (int r = 0; r < 4; ++r) sc_ws[t * 4 + r] = s[r];
    }
}

// ---------------- K2 (k_cg): softmax + context + g2, merged (8 blocks) -------------------
// block (r = b>>1, dh = b&1). Redundant per-block softmax over t from scores ws;
// summation orders preserved exactly from R8's k_ctx/k_g2 (bitwise-identical g2).
__global__ __launch_bounds__(256) void k_cg(const void* __restrict__ te_raw,
                                            const float* __restrict__ sc_ws,
                                            const int* __restrict__ adj,
                                            const void* __restrict__ W2_raw,
                                            const void* __restrict__ gg2_raw,
                                            const void* __restrict__ ga_raw,
                                            const unsigned* __restrict__ graw,
                                            float* __restrict__ g2ws) {
    bool isbf = (graw[0] == 0x3F803F80u);
    __shared__ float s_att[512];
    __shared__ float s_red[256];
    __shared__ float s_part[256];   // [tq][h_local] partials for one 32-h chunk
    __shared__ float s_ctx[512];
    __shared__ float s_p2[2][128];
    int b = blockIdx.x, tid = threadIdx.x;
    int r = b >> 1, dh = b & 1;
    float v0 = sc_ws[tid * 4 + r], v1 = sc_ws[(tid + 256) * 4 + r];
    s_red[tid] = fmaxf(v0, v1);
    __syncthreads();
    for (int st = 128; st > 0; st >>= 1) {
        if (tid < st) s_red[tid] = fmaxf(s_red[tid], s_red[tid + st]);
        __syncthreads();
    }
    float mx = s_red[0];
    __syncthreads();
    float e0 = __expf(v0 - mx), e1 = __expf(v1 - mx);
    s_red[tid] = e0 + e1;
    __syncthreads();
    for (int st = 128; st > 0; st >>= 1) {
        if (tid < st) s_red[tid] += s_red[tid + st];
        __syncthreads();
    }
    float rdn = 1.f / s_red[0];
    __syncthreads();
    s_att[tid] = e0 * rdn;
    s_att[tid + 256] = e1 * rdn;
    __syncthreads();
    // context for this r, all 512 h (16 chunks of 32); order = R8 k_ctx exactly
    int h_local = tid & 31, tq = tid >> 5;
    for (int hc = 0; hc < 16; ++hc) {
        int h = hc * 32 + h_local;
        float acc = 0.f;
        for (int t = tq * 64; t < tq * 64 + 64; ++t)
            acc += s_att[t] * rawf(te_raw, isbf, t * 512 + h);
        s_part[tq * 32 + h_local] = acc;
        __syncthreads();
        if (tid < 32) {
            float c = 0.f;
            #pragma unroll
            for (int s = 0; s < 8; ++s) c += s_part[s * 32 + tid];
            s_ctx[hc * 32 + tid] = c;
        }
        __syncthreads();
    }
    // g2 for (r, dh) d-slice; order = R8 k_g2 exactly
    int dl = tid & 127, th = tid >> 7;
    int d = dh * 128 + dl;
    float acc2 = 0.f;
    for (int h = th * 256; h < th * 256 + 256; ++h)
        acc2 += s_ctx[h] * rawf(W2_raw, isbf, h * 256 + d);
    s_p2[th][dl] = acc2;
    __syncthreads();
    if (th == 0) {
        float tot = s_p2[0][dl] + s_p2[1][dl];
        int ar = adj[r];
        float gav = 1.f / (1.f + expf(-rawf(ga_raw, isbf, ar)));
        g2ws[r * 256 + d] = gav * rawf(gg2_raw, isbf, ar * 256 + d) + (1.f - gav) * tot;
    }
}

// ---------------- K3 (k_fplus): fpt[r][kt][c][kk] = e2[r][j]*(WrT @ entity^T) ------------
// e2 computed inline (256-d dot vs g2, + expf). j = kt*32 + kk.
// Row c=256 carries e2 (denominator), 257..271 are zero.
// R9: body wrapped in rep<2 (idempotent; diagnostic to surface true duration).
__global__ __launch_bounds__(256) void k_fplus(const u16* __restrict__ entity,
                                               const u16* __restrict__ wrt,
                                               const float* __restrict__ g2ws,
                                               u16* __restrict__ fpt) {
    int b = blockIdx.x, tid = threadIdx.x;
    if (b < 256) {
        int r = b & 3, ct = (b >> 2) & 3, jt = b >> 4;
        int c0 = ct * 64, j0 = jt * 256;
        __shared__ __align__(16) u16 lw[64 * 264];  // 64 c-rows x 256 d (+8 pad) bf16
        __shared__ float sg2[256];
        __shared__ float sE[256];                   // e2 for j0..j0+255
        #pragma unroll 1
        for (int rep = 0; rep < 2; ++rep) {
        __syncthreads();
        const u16* wr = wrt + (r * 256 + c0) * 256;
        for (int k = 0; k < 8; ++k) {
            int ci = tid + k * 256; int row = ci >> 5, off = (ci & 31) * 8;
            *(v4i*)(&lw[row * 264 + off]) = *(const v4i*)(wr + row * 256 + off);
        }
        sg2[tid] = g2ws[r * 256 + tid];
        __syncthreads();
        {   // e2 for this block's j-range: thread's own row j0+tid
            const u16* erow = entity + (j0 + tid) * 256;
            float acc = 0.f;
            for (int d0 = 0; d0 < 256; d0 += 8) {
                bf16x8 v = *(const bf16x8*)(erow + d0);
                #pragma unroll
                for (int k = 0; k < 8; ++k) acc += b2f((u16)v[k]) * sg2[d0 + k];
            }
            sE[tid] = expf(acc);
        }
        __syncthreads();
        int wave = tid >> 6, ln = tid & 15, q = (tid & 63) >> 4;
        f32x4 acc[4][4] = {};
        for (int ks = 0; ks < 8; ++ks) {
            bf16x8 afr[4], bfr[4];
            for (int mt = 0; mt < 4; ++mt)
                afr[mt] = *(const bf16x8*)(&lw[(mt * 16 + ln) * 264 + ks * 32 + q * 8]);
            for (int nt = 0; nt < 4; ++nt) {
                int j = j0 + (wave * 4 + nt) * 16 + ln;
                bfr[nt] = *(const bf16x8*)(entity + j * 256 + ks * 32 + q * 8);
            }
            for (int mt = 0; mt < 4; ++mt)
                for (int nt = 0; nt < 4; ++nt)
                    acc[mt][nt] = __builtin_amdgcn_mfma_f32_16x16x32_bf16(afr[mt], bfr[nt], acc[mt][nt], 0, 0, 0);
        }
        for (int nt = 0; nt < 4; ++nt) {
            int j = j0 + (wave * 4 + nt) * 16 + ln;
            float e2j = sE[(wave * 4 + nt) * 16 + ln];
            int kt = j >> 5, kk = j & 31;
            u16* dst = fpt + (((size_t)(r * 128 + kt)) * 272 << 5);
            for (int mt = 0; mt < 4; ++mt)
                for (int reg = 0; reg < 4; ++reg) {
                    int c = c0 + mt * 16 + q * 4 + reg;  // C/D: col=lane&15, row=q*4+reg
                    dst[(c << 5) + kk] = f2b(acc[mt][nt][reg] * e2j);
                }
        }
        }  // rep
    } else {
        // rows c=256..271: c==256 carries e2, rest zero. 8 blocks: (r, half).
        int b2 = b - 256; int r = b2 >> 1, half = b2 & 1;
        __shared__ float sg2z[256];
        __shared__ float sE2[2048];
        #pragma unroll 1
        for (int rep = 0; rep < 2; ++rep) {
        __syncthreads();
        sg2z[tid] = g2ws[r * 256 + tid];
        __syncthreads();
        for (int s = 0; s < 8; ++s) {   // e2 for j in [half*2048, +2048)
            int jj = half * 2048 + s * 256 + tid;
            const u16* erow = entity + jj * 256;
            float acc = 0.f;
            for (int d0 = 0; d0 < 256; d0 += 8) {
                bf16x8 v = *(const bf16x8*)(erow + d0);
                #pragma unroll
                for (int k = 0; k < 8; ++k) acc += b2f((u16)v[k]) * sg2z[d0 + k];
            }
            sE2[s * 256 + tid] = expf(acc);
        }
        __syncthreads();
        for (int it = 0; it < 128; ++it) {
            int l = it * 256 + tid;                 // 0..32767
            int kk = l & 31;
            int c  = 256 + ((l >> 5) & 15);
            int kt = half * 64 + (l >> 9);
            fpt[(((size_t)(r * 128 + kt) * 272 + c) << 5) + kk] =
                (c == 256) ? f2b(sE2[kt * 32 + kk - half * 2048]) : (u16)0;
        }
        }  // rep
    }
}

// ---------------- K4 (k_big): fused[r][i][c] = (M_r @ FplusT^T) / den --------------------
// grid 256: xcd-pinned r so each XCD's L2 holds one fpt_r (2.2 MB < 4 MB).
// BM=64, BN=272 (16 static N-tiles + den tile on ng==3 waves), BK=32, 8 waves.
// R6 schedule (best): coalesced nontemporal mask staging + dbuf lm/lf,
// ONE barrier per K-step, 4-slot static VGPR rotation.
// R9: whole body wrapped in rep<2 (idempotent; diagnostic).
__global__ __launch_bounds__(512) void k_big(const int* __restrict__ masks,
                                             const u16* __restrict__ fpt,
                                             float* __restrict__ fused) {
    __shared__ __align__(16) u16 lm[2][64 * 40];   // mask tile bf16, 80B rows, dbuf
    __shared__ __align__(16) u16 lf[2][272 * 40];  // fpt tile bf16, 80B rows, dbuf
    __shared__ float lden[64];
    int b = blockIdx.x, tid = threadIdx.x;
    int xcd = b & 7; int r = xcd & 3;
    int it = (b >> 3) + ((xcd >> 2) << 5);
    long i0 = (long)it * 64;
    const int* mbase = masks + ((long)r << 24) + i0 * 4096;
    const u16* fbase = fpt + (size_t)r * 128 * 272 * 32;
    int mrow = tid >> 3, mch = tid & 7;          // mask staging: 8 thr/row, 4 ints each
    int wave = tid >> 6, lane = tid & 63, ln = lane & 15, q = lane >> 4;
    int mg = wave >> 2, ng = wave & 3;

    f32x4 acc[2][4];                // static n-tiles (c = ng*64 .. +63)
    f32x4 accD0, accD1;             // den tile (c=256..271), ng==3 waves only

    struct Slot { v4i pm, f0, f1, f2; };
    Slot s0, s1, s2, s3;
    auto load_slot = [&](int kt, Slot& s) {
        s.pm = __builtin_nontemporal_load((const v4i*)(mbase + mrow * 4096 + kt * 32 + mch * 4));
        const u16* su = fbase + (size_t)kt * 8704;   // contiguous 272x32 slab
        s.f0 = *(const v4i*)(su + tid * 8);
        s.f1 = *(const v4i*)(su + (tid + 512) * 8);
        if (tid < 64) s.f2 = *(const v4i*)(su + (tid + 1024) * 8);
    };
    auto stage = [&](int par, const Slot& s) {
        {   // int 0/1 -> bf16 (exact: m * 0x3F80); coalesced slab -> lm[par]
            unsigned m0 = (unsigned)s.pm.x * 0x3F80u, m1 = (unsigned)s.pm.y * 0x3F80u;
            unsigned m2 = (unsigned)s.pm.z * 0x3F80u, m3 = (unsigned)s.pm.w * 0x3F80u;
            v2u w; w.x = m0 | (m1 << 16); w.y = m2 | (m3 << 16);
            *(v2u*)(&lm[par][mrow * 40 + mch * 4]) = w;
        }
        u16* dst = &lf[par][0];
        *(v4i*)(dst + (tid >> 2) * 40 + (tid & 3) * 8) = s.f0;
        { int ci = tid + 512; *(v4i*)(dst + (ci >> 2) * 40 + (ci & 3) * 8) = s.f1; }
        if (tid < 64) { int ci = tid + 1024; *(v4i*)(dst + (ci >> 2) * 40 + (ci & 3) * 8) = s.f2; }
    };
    auto step = [&](int k, Slot& sM, Slot& sF) {
        const u16* msrc = &lm[k & 1][0];
        const u16* src  = &lf[k & 1][0];
        bf16x8 a0 = *(const bf16x8*)(msrc + (mg * 32 + ln) * 40 + q * 8);
        bf16x8 a1 = *(const bf16x8*)(msrc + (mg * 32 + 16 + ln) * 40 + q * 8);
        if (k + 1 < 128) stage((k + 1) & 1, sF);
        if (k + 4 < 128) load_slot(k + 4, sM);
        #pragma unroll
        for (int nt = 0; nt < 4; ++nt) {
            bf16x8 bf = *(const bf16x8*)(src + ((ng * 4 + nt) * 16 + ln) * 40 + q * 8);
            acc[0][nt] = __builtin_amdgcn_mfma_f32_16x16x32_bf16(a0, bf, acc[0][nt], 0, 0, 0);
            acc[1][nt] = __builtin_amdgcn_mfma_f32_16x16x32_bf16(a1, bf, acc[1][nt], 0, 0, 0);
        }
        if (ng == 3) {  // wave-uniform branch: denominator tile (c=256..271)
            bf16x8 bf = *(const bf16x8*)(src + (256 + ln) * 40 + q * 8);
            accD0 = __builtin_amdgcn_mfma_f32_16x16x32_bf16(a0, bf, accD0, 0, 0, 0);
            accD1 = __builtin_amdgcn_mfma_f32_16x16x32_bf16(a1, bf, accD1, 0, 0, 0);
        }
        __syncthreads();
    };

    #pragma unroll 1
    for (int rep = 0; rep < 2; ++rep) {
        __syncthreads();
        #pragma unroll
        for (int mt = 0; mt < 2; ++mt)
            #pragma unroll
            for (int nt = 0; nt < 4; ++nt) acc[mt][nt] = f32x4{0.f, 0.f, 0.f, 0.f};
        accD0 = f32x4{0.f, 0.f, 0.f, 0.f};
        accD1 = f32x4{0.f, 0.f, 0.f, 0.f};

        load_slot(0, s0);
        load_slot(1, s1);
        load_slot(2, s2);
        load_slot(3, s3);
        stage(0, s0);
        __syncthreads();
        #pragma unroll 1
        for (int kt = 0; kt < 128; kt += 4) {
            step(kt,     s0, s1);
            step(kt + 1, s1, s2);
            step(kt + 2, s2, s3);
            step(kt + 3, s3, s0);
        }

        if (ng == 3 && ln == 0) {  // den lives in col 0 of the den tile
            #pragma unroll
            for (int reg = 0; reg < 4; ++reg) {
                lden[mg * 32 + q * 4 + reg]      = accD0[reg];
                lden[mg * 32 + 16 + q * 4 + reg] = accD1[reg];
            }
        }
        __syncthreads();
        float* fb = fused + ((long)r * 4096 + i0) * 256;
        #pragma unroll
        for (int mt = 0; mt < 2; ++mt) {
            float rd[4];
            #pragma unroll
            for (int reg = 0; reg < 4; ++reg) rd[reg] = 1.0f / lden[mg * 32 + mt * 16 + q * 4 + reg];
            #pragma unroll
            for (int nt = 0; nt < 4; ++nt) {
                int c = (ng * 4 + nt) * 16 + ln;
                #pragma unroll
                for (int reg = 0; reg < 4; ++reg) {
                    int row = mg * 32 + mt * 16 + q * 4 + reg;
                    __builtin_nontemporal_store(acc[mt][nt][reg] * rd[reg], fb + row * 256 + c);
                }
            }
        }
    }  // rep
}

// ---------------- K5 (k_ln): out = relu(LN(sum_r fused[r])), raw gamma/beta --------------
__global__ __launch_bounds__(256) void k_ln(const float* __restrict__ fused,
                                            const void* __restrict__ gamma_raw,
                                            const void* __restrict__ beta_raw,
                                            const unsigned* __restrict__ graw,
                                            void* __restrict__ outraw) {
    __shared__ float part[8];
    int i = blockIdx.x, o = threadIdx.x;
    bool isbf = (graw[0] == 0x3F803F80u);
    float x = 0.f;
    for (int r = 0; r < 4; ++r)
        x += __builtin_nontemporal_load(fused + ((long)(r << 12) + i) * 256 + o);
    float s = x;
    #pragma unroll
    for (int st = 32; st > 0; st >>= 1) s += __shfl_xor(s, st);
    int w = o >> 6;
    if ((o & 63) == 0) part[w] = s;
    __syncthreads();
    float mu = (part[0] + part[1] + part[2] + part[3]) * (1.f / 256.f);
    float v = x - mu;
    float qv = v * v;
    #pragma unroll
    for (int st = 32; st > 0; st >>= 1) qv += __shfl_xor(qv, st);
    if ((o & 63) == 0) part[4 + w] = qv;
    __syncthreads();
    float var = (part[4] + part[5] + part[6] + part[7]) * (1.f / 256.f);
    float y = v * rsqrtf(var + 1e-5f) * rawf(gamma_raw, isbf, o) + rawf(beta_raw, isbf, o);
    float res = fmaxf(y, 0.f);
    if (isbf) ((u16*)outraw)[i * 256 + o] = f2b(res);
    else      ((float*)outraw)[i * 256 + o] = res;
}

extern "C" void kernel_launch(void* const* d_in, const int* in_sizes, int n_in,
                              void* d_out, int out_size, void* d_ws, size_t ws_size,
                              hipStream_t stream) {
    const int* adj   = (const int*)d_in[2];
    const int* masks = (const int*)d_in[3];
    const unsigned* graw = (const unsigned*)d_in[12];  // ln_gamma raw word (dtype probe)
    char* ws = (char*)d_ws;
    float* g2ws = (float*)(ws + G2_OFF);
    float* scws = (float*)(ws + SC_OFF);
    u16*   wrt  = (u16*)(ws + WRT_OFF);
    u16*   fpt  = (u16*)(ws + FPT_OFF);
    float* fus  = (float*)(ws + FUSED_OFF);
    u16*   ent  = (u16*)(ws + CAN_OFF);

    // d_in[5] (graph_guids_1) and d_in[10] (W_1) are dead: s1 cancels in softmax.
    k_front<<<416, 512, 0, stream>>>(d_in[0], d_in[1], adj, d_in[4],
                                     d_in[8], d_in[9], graw, ent, scws, wrt);
    k_cg<<<8, 256, 0, stream>>>(d_in[1], scws, adj, d_in[11], d_in[6], d_in[7],
                                graw, g2ws);
    k_fplus<<<264, 256, 0, stream>>>(ent, wrt, g2ws, fpt);
    k_big<<<256, 512, 0, stream>>>(masks, fpt, fus);
    k_ln<<<4096, 256, 0, stream>>>(fus, d_in[12], d_in[13], graw, d_out);
}

// Round 7
// 742.139 us; speedup vs baseline: 2.2417x; 2.2417x over previous
//
#include <hip/hip_runtime.h>
#include <hip/hip_bf16.h>

// TextRelationalGraphAttention on MI355X.
// Sizes: N=4096, D=O=256, 2H=512, T=512, S=8, R=4, BN=2.
// Float input dtype (f32 vs bf16) detected at runtime from ln_gamma (= ones):
// first u32 word is 0x3F803F80 (bf16) vs 0x3F800000 (f32).
//
// Math: s1 cancels in softmax over j (W_1/graph_guids_1 dead);
// fused[r,i,:] = (M_r @ (e2_r*EW_r)) / (M_r @ e2_r); basis W folded into EW.
//
// R10 (post-mortem R9 diagnostic: k_fplus ~450us/rep at 0.94% occupancy =
// 8 else-branch straggler blocks doing 2048 gather-dots each on an empty
// device; e2 row-dot gathers shatter to 64 lines/instr at 512B lane stride):
//  - k_fplus restructured: 256 uniform blocks x 512 thr (8 waves).
//    e2 computed in-block wave-parallel: per row, 64 lanes x 4 d COALESCED
//    (one 512B row per dwordx2 instr) + butterfly shfl reduce. ct==0 blocks
//    also write the e2/zero rows (c=256..271) for their jt. Else blocks GONE.
//  - k_big: rep<2 diagnostic reverted (R6-best single-shot schedule).
//  - k_front / k_cg / k_ln unchanged from R9.

typedef unsigned short u16;
typedef short bf16x8 __attribute__((ext_vector_type(8)));   // 8 bf16 = 4 VGPRs (MFMA A/B frag)
typedef float f32x4 __attribute__((ext_vector_type(4)));    // MFMA C/D frag
typedef float f32x8 __attribute__((ext_vector_type(8)));
typedef int   v4i   __attribute__((ext_vector_type(4)));    // 16B load/store
typedef unsigned int v2u __attribute__((ext_vector_type(2)));

// ws layout (bytes)
#define G2_OFF    0          // [4][256] f32
#define SC_OFF    4096       // scores [512 t][4 r] f32
#define WRT_OFF   69632      // [4][256 c][256 d] bf16
#define FPT_OFF   593920     // [4][128 kt][272 c][32 kk] bf16 (c=256 row = e2, 257..271 = 0)
#define FUSED_OFF 9506816    // [4][4096 i][256 c] f32
#define CAN_OFF   26284032   // canonical bf16 entity [4096*256]

__device__ __forceinline__ float b2f(u16 u) {
    union { unsigned int i; float f; } v; v.i = ((unsigned int)u) << 16; return v.f;
}
__device__ __forceinline__ u16 f2b(float f) {  // RNE, finite inputs only
    union { float f; unsigned int i; } v; v.f = f;
    return (u16)((v.i + 0x7FFFu + ((v.i >> 16) & 1u)) >> 16);
}
__device__ __forceinline__ float rawf(const void* p, bool isbf, int i) {
    return isbf ? b2f(((const u16*)p)[i]) : ((const float*)p)[i];
}
__device__ __forceinline__ f32x8 raw8(const void* p, bool isbf, int i8) {  // i8 % 8 == 0
    f32x8 o;
    if (isbf) {
        bf16x8 v = *(const bf16x8*)((const u16*)p + i8);
        #pragma unroll
        for (int k = 0; k < 8; ++k) o[k] = b2f((u16)v[k]);
    } else {
        const float* f = (const float*)p + i8;
        float4 a = *(const float4*)f, b = *(const float4*)(f + 4);
        o[0] = a.x; o[1] = a.y; o[2] = a.z; o[3] = a.w;
        o[4] = b.x; o[5] = b.y; o[6] = b.z; o[7] = b.w;
    }
    return o;
}

// ---------------- K1 (k_front): entity-cvt + WrT + scores, one launch --------------------
// blocks 0..255: entity cvt. 256..383: wrt. 384..415: scores (16 t-rows each).
__global__ __launch_bounds__(512) void k_front(
    const void* __restrict__ ent_raw, const void* __restrict__ te_raw,
    const int* __restrict__ adj, const void* __restrict__ tg_raw,
    const void* __restrict__ bV_raw, const void* __restrict__ bb_raw,
    const unsigned* __restrict__ graw,
    u16* __restrict__ ent_can, float* __restrict__ sc_ws, u16* __restrict__ wrt)
{
    bool isbf = (graw[0] == 0x3F803F80u);
    int b = blockIdx.x, tid = threadIdx.x;
    if (b < 256) {               // ---- entity canonicalize: 256 blk x 512 thr x 8 elems
        int base = b * 4096 + tid;
        if (isbf) {
            const u16* s = (const u16*)ent_raw;
            #pragma unroll
            for (int k = 0; k < 8; ++k) { int i = base + k * 512; ent_can[i] = s[i]; }
        } else {
            const float* s = (const float*)ent_raw;
            #pragma unroll
            for (int k = 0; k < 8; ++k) { int i = base + k * 512; ent_can[i] = f2b(s[i]); }
        }
        return;
    }
    if (b < 384) {               // ---- WrT[r][c][d] = sum_b bb[adj[d%4],b] * bV[64r+d/4,b,c]
        int b2 = b - 256;
        int r = b2 >> 5, cq = b2 & 31;
        int c = cq * 8 + (tid >> 6);
        int dq = tid & 63;       // d/4
        int a[4] = {adj[0], adj[1], adj[2], adj[3]};
        #pragma unroll
        for (int dd = 0; dd < 4; ++dd) {
            float w = 0.f;
            #pragma unroll
            for (int bi = 0; bi < 2; ++bi)
                w += rawf(bb_raw, isbf, a[dd] * 2 + bi) *
                     rawf(bV_raw, isbf, ((64 * r + dq) * 2 + bi) * 256 + c);
            wrt[(r * 256 + c) * 256 + dq * 4 + dd] = f2b(w);
        }
        return;
    }
    // ---- scores[t][r] = te[t,:] . tg[r,:], 32 blocks x 16 t-rows
    __shared__ float s_tg[4 * 512];
    int a[4] = {adj[0], adj[1], adj[2], adj[3]};
    for (int idx = tid; idx < 2048; idx += 512) {
        int r = idx >> 9, h = idx & 511;
        s_tg[r * 512 + h] = rawf(tg_raw, isbf, a[r] * 512 + h);
    }
    __syncthreads();
    int b2 = b - 384;
    int t = b2 * 16 + (tid >> 5);      // 16 t per block, 32 lanes per t
    int h0 = (tid & 31) * 16;          // each lane: 16 h's
    float s[4] = {0.f, 0.f, 0.f, 0.f};
    #pragma unroll
    for (int half = 0; half < 2; ++half) {
        f32x8 v = raw8(te_raw, isbf, t * 512 + h0 + half * 8);
        #pragma unroll
        for (int k = 0; k < 8; ++k) {
            float tv = v[k]; int h = h0 + half * 8 + k;
            #pragma unroll
            for (int r = 0; r < 4; ++r) s[r] += tv * s_tg[r * 512 + h];
        }
    }
    #pragma unroll
    for (int r = 0; r < 4; ++r) {      // reduce across the 32-lane h-split
        #pragma unroll
        for (int m = 16; m > 0; m >>= 1) s[r] += __shfl_xor(s[r], m);
    }
    if ((tid & 31) == 0) {
        #pragma unroll
        for (int r = 0; r < 4; ++r) sc_ws[t * 4 + r] = s[r];
    }
}

// ---------------- K2 (k_cg): softmax + context + g2, merged (8 blocks) -------------------
// block (r = b>>1, dh = b&1). Redundant per-block softmax over t from scores ws;
// summation orders preserved exactly from R8's k_ctx/k_g2 (bitwise-identical g2).
__global__ __launch_bounds__(256) void k_cg(const void* __restrict__ te_raw,
                                            const float* __restrict__ sc_ws,
                                            const int* __restrict__ adj,
                                            const void* __restrict__ W2_raw,
                                            const void* __restrict__ gg2_raw,
                                            const void* __restrict__ ga_raw,
                                            const unsigned* __restrict__ graw,
                                            float* __restrict__ g2ws) {
    bool isbf = (graw[0] == 0x3F803F80u);
    __shared__ float s_att[512];
    __shared__ float s_red[256];
    __shared__ float s_part[256];   // [tq][h_local] partials for one 32-h chunk
    __shared__ float s_ctx[512];
    __shared__ float s_p2[2][128];
    int b = blockIdx.x, tid = threadIdx.x;
    int r = b >> 1, dh = b & 1;
    float v0 = sc_ws[tid * 4 + r], v1 = sc_ws[(tid + 256) * 4 + r];
    s_red[tid] = fmaxf(v0, v1);
    __syncthreads();
    for (int st = 128; st > 0; st >>= 1) {
        if (tid < st) s_red[tid] = fmaxf(s_red[tid], s_red[tid + st]);
        __syncthreads();
    }
    float mx = s_red[0];
    __syncthreads();
    float e0 = __expf(v0 - mx), e1 = __expf(v1 - mx);
    s_red[tid] = e0 + e1;
    __syncthreads();
    for (int st = 128; st > 0; st >>= 1) {
        if (tid < st) s_red[tid] += s_red[tid + st];
        __syncthreads();
    }
    float rdn = 1.f / s_red[0];
    __syncthreads();
    s_att[tid] = e0 * rdn;
    s_att[tid + 256] = e1 * rdn;
    __syncthreads();
    // context for this r, all 512 h (16 chunks of 32); order preserved
    int h_local = tid & 31, tq = tid >> 5;
    for (int hc = 0; hc < 16; ++hc) {
        int h = hc * 32 + h_local;
        float acc = 0.f;
        for (int t = tq * 64; t < tq * 64 + 64; ++t)
            acc += s_att[t] * rawf(te_raw, isbf, t * 512 + h);
        s_part[tq * 32 + h_local] = acc;
        __syncthreads();
        if (tid < 32) {
            float c = 0.f;
            #pragma unroll
            for (int s = 0; s < 8; ++s) c += s_part[s * 32 + tid];
            s_ctx[hc * 32 + tid] = c;
        }
        __syncthreads();
    }
    // g2 for (r, dh) d-slice; order preserved
    int dl = tid & 127, th = tid >> 7;
    int d = dh * 128 + dl;
    float acc2 = 0.f;
    for (int h = th * 256; h < th * 256 + 256; ++h)
        acc2 += s_ctx[h] * rawf(W2_raw, isbf, h * 256 + d);
    s_p2[th][dl] = acc2;
    __syncthreads();
    if (th == 0) {
        float tot = s_p2[0][dl] + s_p2[1][dl];
        int ar = adj[r];
        float gav = 1.f / (1.f + expf(-rawf(ga_raw, isbf, ar)));
        g2ws[r * 256 + d] = gav * rawf(gg2_raw, isbf, ar * 256 + d) + (1.f - gav) * tot;
    }
}

// ---------------- K3 (k_fplus): fpt[r][kt][c][kk] = e2[r][j]*(WrT @ entity^T) ------------
// R10: 256 UNIFORM blocks (r = b&3, ct = (b>>2)&3, jt = b>>4) x 512 thr (8 waves).
// e2 computed in-block wave-parallel with COALESCED row loads (64 lanes x 4 d =
// one 512B row per instr) + butterfly shfl reduce; ct-blocks redundantly compute
// their 256 e2's (us-cheap, keeps blocks uniform). ct==0 blocks also write the
// denominator rows c=256..271 for their jt. j = kt*32 + kk.
__global__ __launch_bounds__(512) void k_fplus(const u16* __restrict__ entity,
                                               const u16* __restrict__ wrt,
                                               const float* __restrict__ g2ws,
                                               u16* __restrict__ fpt) {
    int b = blockIdx.x, tid = threadIdx.x;
    int r = b & 3, ct = (b >> 2) & 3, jt = b >> 4;
    int c0 = ct * 64, j0 = jt * 256;
    __shared__ __align__(16) u16 lw[64 * 264];  // 64 c-rows x 256 d (+8 pad) bf16
    __shared__ float sg2[256];
    __shared__ float sE[256];                   // e2 for j0..j0+255
    const u16* wr = wrt + (r * 256 + c0) * 256;
    #pragma unroll
    for (int k = 0; k < 4; ++k) {
        int ci = tid + k * 512; int row = ci >> 5, off = (ci & 31) * 8;
        *(v4i*)(&lw[row * 264 + off]) = *(const v4i*)(wr + row * 256 + off);
    }
    if (tid < 256) sg2[tid] = g2ws[r * 256 + tid];
    __syncthreads();
    int wv = tid >> 6, lane = tid & 63, ln = lane & 15, q = lane >> 4;
    {   // e2: wave wv covers rows j0 + wv*32 .. +31; per row one coalesced 512B load
        float gl0 = sg2[lane * 4 + 0], gl1 = sg2[lane * 4 + 1];
        float gl2 = sg2[lane * 4 + 2], gl3 = sg2[lane * 4 + 3];
        #pragma unroll 4
        for (int i = 0; i < 32; ++i) {
            int row = j0 + wv * 32 + i;
            v2u e4 = *(const v2u*)(entity + row * 256 + lane * 4);
            float s = b2f((u16)(e4.x & 0xFFFFu)) * gl0
                    + b2f((u16)(e4.x >> 16))     * gl1
                    + b2f((u16)(e4.y & 0xFFFFu)) * gl2
                    + b2f((u16)(e4.y >> 16))     * gl3;
            #pragma unroll
            for (int m = 32; m > 0; m >>= 1) s += __shfl_xor(s, m);
            if (lane == 0) sE[wv * 32 + i] = expf(s);
        }
    }
    __syncthreads();
    f32x4 acc[4][2] = {};
    for (int ks = 0; ks < 8; ++ks) {
        bf16x8 afr[4], bfr[2];
        #pragma unroll
        for (int mt = 0; mt < 4; ++mt)
            afr[mt] = *(const bf16x8*)(&lw[(mt * 16 + ln) * 264 + ks * 32 + q * 8]);
        #pragma unroll
        for (int nt = 0; nt < 2; ++nt) {
            int j = j0 + (wv * 2 + nt) * 16 + ln;
            bfr[nt] = *(const bf16x8*)(entity + j * 256 + ks * 32 + q * 8);
        }
        #pragma unroll
        for (int mt = 0; mt < 4; ++mt)
            #pragma unroll
            for (int nt = 0; nt < 2; ++nt)
                acc[mt][nt] = __builtin_amdgcn_mfma_f32_16x16x32_bf16(afr[mt], bfr[nt], acc[mt][nt], 0, 0, 0);
    }
    #pragma unroll
    for (int nt = 0; nt < 2; ++nt) {
        int jl = (wv * 2 + nt) * 16 + ln;
        int j = j0 + jl;
        float e2j = sE[jl];
        int kt = j >> 5, kk = j & 31;
        u16* dst = fpt + (((size_t)(r * 128 + kt)) * 272 << 5);
        #pragma unroll
        for (int mt = 0; mt < 4; ++mt)
            #pragma unroll
            for (int reg = 0; reg < 4; ++reg) {
                int c = c0 + mt * 16 + q * 4 + reg;  // C/D: col=lane&15, row=q*4+reg
                dst[(c << 5) + kk] = f2b(acc[mt][nt][reg] * e2j);
            }
    }
    if (ct == 0) {  // denominator rows for this (r, jt): c==256 carries e2, 257..271 zero
        #pragma unroll
        for (int s = 0; s < 8; ++s) {
            int l = s * 512 + tid;               // 0..4095 = [ktl 8][cl 16][kk 32]
            int kk = l & 31, cl = (l >> 5) & 15, ktl = l >> 9;
            int kt = jt * 8 + ktl;
            fpt[(((size_t)(r * 128 + kt) * 272 + 256 + cl) << 5) + kk] =
                (cl == 0) ? f2b(sE[ktl * 32 + kk]) : (u16)0;
        }
    }
}

// ---------------- K4 (k_big): fused[r][i][c] = (M_r @ FplusT^T) / den --------------------
// grid 256: xcd-pinned r so each XCD's L2 holds one fpt_r (2.2 MB < 4 MB).
// BM=64, BN=272 (16 static N-tiles + den tile on ng==3 waves), BK=32, 8 waves.
// R6 schedule (best): coalesced nontemporal mask staging + dbuf lm/lf,
// ONE barrier per K-step, 4-slot static VGPR rotation.
__global__ __launch_bounds__(512) void k_big(const int* __restrict__ masks,
                                             const u16* __restrict__ fpt,
                                             float* __restrict__ fused) {
    __shared__ __align__(16) u16 lm[2][64 * 40];   // mask tile bf16, 80B rows, dbuf
    __shared__ __align__(16) u16 lf[2][272 * 40];  // fpt tile bf16, 80B rows, dbuf
    __shared__ float lden[64];
    int b = blockIdx.x, tid = threadIdx.x;
    int xcd = b & 7; int r = xcd & 3;
    int it = (b >> 3) + ((xcd >> 2) << 5);
    long i0 = (long)it * 64;
    const int* mbase = masks + ((long)r << 24) + i0 * 4096;
    const u16* fbase = fpt + (size_t)r * 128 * 272 * 32;
    int mrow = tid >> 3, mch = tid & 7;          // mask staging: 8 thr/row, 4 ints each
    int wave = tid >> 6, lane = tid & 63, ln = lane & 15, q = lane >> 4;
    int mg = wave >> 2, ng = wave & 3;

    f32x4 acc[2][4] = {};           // static n-tiles (c = ng*64 .. +63)
    f32x4 accD0 = {}, accD1 = {};   // den tile (c=256..271), ng==3 waves only

    struct Slot { v4i pm, f0, f1, f2; };
    Slot s0, s1, s2, s3;
    auto load_slot = [&](int kt, Slot& s) {
        s.pm = __builtin_nontemporal_load((const v4i*)(mbase + mrow * 4096 + kt * 32 + mch * 4));
        const u16* su = fbase + (size_t)kt * 8704;   // contiguous 272x32 slab
        s.f0 = *(const v4i*)(su + tid * 8);
        s.f1 = *(const v4i*)(su + (tid + 512) * 8);
        if (tid < 64) s.f2 = *(const v4i*)(su + (tid + 1024) * 8);
    };
    auto stage = [&](int par, const Slot& s) {
        {   // int 0/1 -> bf16 (exact: m * 0x3F80); coalesced slab -> lm[par]
            unsigned m0 = (unsigned)s.pm.x * 0x3F80u, m1 = (unsigned)s.pm.y * 0x3F80u;
            unsigned m2 = (unsigned)s.pm.z * 0x3F80u, m3 = (unsigned)s.pm.w * 0x3F80u;
            v2u w; w.x = m0 | (m1 << 16); w.y = m2 | (m3 << 16);
            *(v2u*)(&lm[par][mrow * 40 + mch * 4]) = w;
        }
        u16* dst = &lf[par][0];
        *(v4i*)(dst + (tid >> 2) * 40 + (tid & 3) * 8) = s.f0;
        { int ci = tid + 512; *(v4i*)(dst + (ci >> 2) * 40 + (ci & 3) * 8) = s.f1; }
        if (tid < 64) { int ci = tid + 1024; *(v4i*)(dst + (ci >> 2) * 40 + (ci & 3) * 8) = s.f2; }
    };
    auto step = [&](int k, Slot& sM, Slot& sF) {
        const u16* msrc = &lm[k & 1][0];
        const u16* src  = &lf[k & 1][0];
        bf16x8 a0 = *(const bf16x8*)(msrc + (mg * 32 + ln) * 40 + q * 8);
        bf16x8 a1 = *(const bf16x8*)(msrc + (mg * 32 + 16 + ln) * 40 + q * 8);
        if (k + 1 < 128) stage((k + 1) & 1, sF);
        if (k + 4 < 128) load_slot(k + 4, sM);
        #pragma unroll
        for (int nt = 0; nt < 4; ++nt) {
            bf16x8 bf = *(const bf16x8*)(src + ((ng * 4 + nt) * 16 + ln) * 40 + q * 8);
            acc[0][nt] = __builtin_amdgcn_mfma_f32_16x16x32_bf16(a0, bf, acc[0][nt], 0, 0, 0);
            acc[1][nt] = __builtin_amdgcn_mfma_f32_16x16x32_bf16(a1, bf, acc[1][nt], 0, 0, 0);
        }
        if (ng == 3) {  // wave-uniform branch: denominator tile (c=256..271)
            bf16x8 bf = *(const bf16x8*)(src + (256 + ln) * 40 + q * 8);
            accD0 = __builtin_amdgcn_mfma_f32_16x16x32_bf16(a0, bf, accD0, 0, 0, 0);
            accD1 = __builtin_amdgcn_mfma_f32_16x16x32_bf16(a1, bf, accD1, 0, 0, 0);
        }
        __syncthreads();
    };

    load_slot(0, s0);
    load_slot(1, s1);
    load_slot(2, s2);
    load_slot(3, s3);
    stage(0, s0);
    __syncthreads();
    #pragma unroll 1
    for (int kt = 0; kt < 128; kt += 4) {
        step(kt,     s0, s1);
        step(kt + 1, s1, s2);
        step(kt + 2, s2, s3);
        step(kt + 3, s3, s0);
    }

    if (ng == 3 && ln == 0) {  // den lives in col 0 of the den tile
        #pragma unroll
        for (int reg = 0; reg < 4; ++reg) {
            lden[mg * 32 + q * 4 + reg]      = accD0[reg];
            lden[mg * 32 + 16 + q * 4 + reg] = accD1[reg];
        }
    }
    __syncthreads();
    float* fb = fused + ((long)r * 4096 + i0) * 256;
    #pragma unroll
    for (int mt = 0; mt < 2; ++mt) {
        float rd[4];
        #pragma unroll
        for (int reg = 0; reg < 4; ++reg) rd[reg] = 1.0f / lden[mg * 32 + mt * 16 + q * 4 + reg];
        #pragma unroll
        for (int nt = 0; nt < 4; ++nt) {
            int c = (ng * 4 + nt) * 16 + ln;
            #pragma unroll
            for (int reg = 0; reg < 4; ++reg) {
                int row = mg * 32 + mt * 16 + q * 4 + reg;
                __builtin_nontemporal_store(acc[mt][nt][reg] * rd[reg], fb + row * 256 + c);
            }
        }
    }
}

// ---------------- K5 (k_ln): out = relu(LN(sum_r fused[r])), raw gamma/beta --------------
__global__ __launch_bounds__(256) void k_ln(const float* __restrict__ fused,
                                            const void* __restrict__ gamma_raw,
                                            const void* __restrict__ beta_raw,
                                            const unsigned* __restrict__ graw,
                                            void* __restrict__ outraw) {
    __shared__ float part[8];
    int i = blockIdx.x, o = threadIdx.x;
    bool isbf = (graw[0] == 0x3F803F80u);
    float x = 0.f;
    for (int r = 0; r < 4; ++r)
        x += __builtin_nontemporal_load(fused + ((long)(r << 12) + i) * 256 + o);
    float s = x;
    #pragma unroll
    for (int st = 32; st > 0; st >>= 1) s += __shfl_xor(s, st);
    int w = o >> 6;
    if ((o & 63) == 0) part[w] = s;
    __syncthreads();
    float mu = (part[0] + part[1] + part[2] + part[3]) * (1.f / 256.f);
    float v = x - mu;
    float qv = v * v;
    #pragma unroll
    for (int st = 32; st > 0; st >>= 1) qv += __shfl_xor(qv, st);
    if ((o & 63) == 0) part[4 + w] = qv;
    __syncthreads();
    float var = (part[4] + part[5] + part[6] + part[7]) * (1.f / 256.f);
    float y = v * rsqrtf(var + 1e-5f) * rawf(gamma_raw, isbf, o) + rawf(beta_raw, isbf, o);
    float res = fmaxf(y, 0.f);
    if (isbf) ((u16*)outraw)[i * 256 + o] = f2b(res);
    else      ((float*)outraw)[i * 256 + o] = res;
}

extern "C" void kernel_launch(void* const* d_in, const int* in_sizes, int n_in,
                              void* d_out, int out_size, void* d_ws, size_t ws_size,
                              hipStream_t stream) {
    const int* adj   = (const int*)d_in[2];
    const int* masks = (const int*)d_in[3];
    const unsigned* graw = (const unsigned*)d_in[12];  // ln_gamma raw word (dtype probe)
    char* ws = (char*)d_ws;
    float* g2ws = (float*)(ws + G2_OFF);
    float* scws = (float*)(ws + SC_OFF);
    u16*   wrt  = (u16*)(ws + WRT_OFF);
    u16*   fpt  = (u16*)(ws + FPT_OFF);
    float* fus  = (float*)(ws + FUSED_OFF);
    u16*   ent  = (u16*)(ws + CAN_OFF);

    // d_in[5] (graph_guids_1) and d_in[10] (W_1) are dead: s1 cancels in softmax.
    k_front<<<416, 512, 0, stream>>>(d_in[0], d_in[1], adj, d_in[4],
                                     d_in[8], d_in[9], graw, ent, scws, wrt);
    k_cg<<<8, 256, 0, stream>>>(d_in[1], scws, adj, d_in[11], d_in[6], d_in[7],
                                graw, g2ws);
    k_fplus<<<256, 512, 0, stream>>>(ent, wrt, g2ws, fpt);
    k_big<<<256, 512, 0, stream>>>(masks, fpt, fus);
    k_ln<<<4096, 256, 0, stream>>>(fus, d_in[12], d_in[13], graw, d_out);
}

// Round 8
// 487.860 us; speedup vs baseline: 3.4102x; 1.5212x over previous
//
#include <hip/hip_runtime.h>
#include <hip/hip_bf16.h>

// TextRelationalGraphAttention on MI355X.
// Sizes: N=4096, D=O=256, 2H=512, T=512, S=8, R=4, BN=2.
// Float input dtype (f32 vs bf16) detected at runtime from ln_gamma (= ones):
// first u32 word is 0x3F803F80 (bf16) vs 0x3F800000 (f32).
//
// Math: s1 cancels in softmax over j (W_1/graph_guids_1 dead);
// fused[r,i,:] = (M_r @ (e2_r*EW_r)) / (M_r @ e2_r); basis W folded into EW.
//
// R11 (post-mortem R10: k_cg exposed at 302us, 8 blocks @ 0.37% occupancy —
// the R9 merge multiplied per-block context work 16x; third straggler of the
// session after k_pre [R7] and k_fplus else-blocks [R9]):
//  - k_cg split back apart and parallelized:
//      k_ctx: 256 blocks (r x 64 h-chunks of 8). Per-block redundant softmax
//      from scores ws (~us), 16 te loads/thread, 32-group LDS reduce.
//      k_g2: R8's 8-block version (reads ctx ws; never visible).
//  - k_front / k_fplus (R10 uniform+coalesced) / k_big (R6 dbuf) / k_ln kept.

typedef unsigned short u16;
typedef short bf16x8 __attribute__((ext_vector_type(8)));   // 8 bf16 = 4 VGPRs (MFMA A/B frag)
typedef float f32x4 __attribute__((ext_vector_type(4)));    // MFMA C/D frag
typedef float f32x8 __attribute__((ext_vector_type(8)));
typedef int   v4i   __attribute__((ext_vector_type(4)));    // 16B load/store
typedef unsigned int v2u __attribute__((ext_vector_type(2)));

// ws layout (bytes)
#define G2_OFF    0          // [4][256] f32
#define SC_OFF    4096       // scores [512 t][4 r] f32
#define CTX_OFF   16384      // ctx [4 r][512 h] f32
#define WRT_OFF   69632      // [4][256 c][256 d] bf16
#define FPT_OFF   593920     // [4][128 kt][272 c][32 kk] bf16 (c=256 row = e2, 257..271 = 0)
#define FUSED_OFF 9506816    // [4][4096 i][256 c] f32
#define CAN_OFF   26284032   // canonical bf16 entity [4096*256]

__device__ __forceinline__ float b2f(u16 u) {
    union { unsigned int i; float f; } v; v.i = ((unsigned int)u) << 16; return v.f;
}
__device__ __forceinline__ u16 f2b(float f) {  // RNE, finite inputs only
    union { float f; unsigned int i; } v; v.f = f;
    return (u16)((v.i + 0x7FFFu + ((v.i >> 16) & 1u)) >> 16);
}
__device__ __forceinline__ float rawf(const void* p, bool isbf, int i) {
    return isbf ? b2f(((const u16*)p)[i]) : ((const float*)p)[i];
}
__device__ __forceinline__ f32x8 raw8(const void* p, bool isbf, int i8) {  // i8 % 8 == 0
    f32x8 o;
    if (isbf) {
        bf16x8 v = *(const bf16x8*)((const u16*)p + i8);
        #pragma unroll
        for (int k = 0; k < 8; ++k) o[k] = b2f((u16)v[k]);
    } else {
        const float* f = (const float*)p + i8;
        float4 a = *(const float4*)f, b = *(const float4*)(f + 4);
        o[0] = a.x; o[1] = a.y; o[2] = a.z; o[3] = a.w;
        o[4] = b.x; o[5] = b.y; o[6] = b.z; o[7] = b.w;
    }
    return o;
}

// ---------------- K1 (k_front): entity-cvt + WrT + scores, one launch --------------------
// blocks 0..255: entity cvt. 256..383: wrt. 384..415: scores (16 t-rows each).
__global__ __launch_bounds__(512) void k_front(
    const void* __restrict__ ent_raw, const void* __restrict__ te_raw,
    const int* __restrict__ adj, const void* __restrict__ tg_raw,
    const void* __restrict__ bV_raw, const void* __restrict__ bb_raw,
    const unsigned* __restrict__ graw,
    u16* __restrict__ ent_can, float* __restrict__ sc_ws, u16* __restrict__ wrt)
{
    bool isbf = (graw[0] == 0x3F803F80u);
    int b = blockIdx.x, tid = threadIdx.x;
    if (b < 256) {               // ---- entity canonicalize: 256 blk x 512 thr x 8 elems
        int base = b * 4096 + tid;
        if (isbf) {
            const u16* s = (const u16*)ent_raw;
            #pragma unroll
            for (int k = 0; k < 8; ++k) { int i = base + k * 512; ent_can[i] = s[i]; }
        } else {
            const float* s = (const float*)ent_raw;
            #pragma unroll
            for (int k = 0; k < 8; ++k) { int i = base + k * 512; ent_can[i] = f2b(s[i]); }
        }
        return;
    }
    if (b < 384) {               // ---- WrT[r][c][d] = sum_b bb[adj[d%4],b] * bV[64r+d/4,b,c]
        int b2 = b - 256;
        int r = b2 >> 5, cq = b2 & 31;
        int c = cq * 8 + (tid >> 6);
        int dq = tid & 63;       // d/4
        int a[4] = {adj[0], adj[1], adj[2], adj[3]};
        #pragma unroll
        for (int dd = 0; dd < 4; ++dd) {
            float w = 0.f;
            #pragma unroll
            for (int bi = 0; bi < 2; ++bi)
                w += rawf(bb_raw, isbf, a[dd] * 2 + bi) *
                     rawf(bV_raw, isbf, ((64 * r + dq) * 2 + bi) * 256 + c);
            wrt[(r * 256 + c) * 256 + dq * 4 + dd] = f2b(w);
        }
        return;
    }
    // ---- scores[t][r] = te[t,:] . tg[r,:], 32 blocks x 16 t-rows
    __shared__ float s_tg[4 * 512];
    int a[4] = {adj[0], adj[1], adj[2], adj[3]};
    for (int idx = tid; idx < 2048; idx += 512) {
        int r = idx >> 9, h = idx & 511;
        s_tg[r * 512 + h] = rawf(tg_raw, isbf, a[r] * 512 + h);
    }
    __syncthreads();
    int b2 = b - 384;
    int t = b2 * 16 + (tid >> 5);      // 16 t per block, 32 lanes per t
    int h0 = (tid & 31) * 16;          // each lane: 16 h's
    float s[4] = {0.f, 0.f, 0.f, 0.f};
    #pragma unroll
    for (int half = 0; half < 2; ++half) {
        f32x8 v = raw8(te_raw, isbf, t * 512 + h0 + half * 8);
        #pragma unroll
        for (int k = 0; k < 8; ++k) {
            float tv = v[k]; int h = h0 + half * 8 + k;
            #pragma unroll
            for (int r = 0; r < 4; ++r) s[r] += tv * s_tg[r * 512 + h];
        }
    }
    #pragma unroll
    for (int r = 0; r < 4; ++r) {      // reduce across the 32-lane h-split
        #pragma unroll
        for (int m = 16; m > 0; m >>= 1) s[r] += __shfl_xor(s[r], m);
    }
    if ((tid & 31) == 0) {
        #pragma unroll
        for (int r = 0; r < 4; ++r) sc_ws[t * 4 + r] = s[r];
    }
}

// ---------------- K2 (k_ctx): softmax (redundant/block) + context, 256 blocks ------------
// block = (r = b>>6, hc = b&63): 8 h-columns. 32 t-groups x 16 t per thread.
__global__ __launch_bounds__(256) void k_ctx(const void* __restrict__ te_raw,
                                             const float* __restrict__ sc_ws,
                                             const unsigned* __restrict__ graw,
                                             float* __restrict__ ctx_ws) {
    bool isbf = (graw[0] == 0x3F803F80u);
    __shared__ float s_att[512];
    __shared__ float s_red[256];
    __shared__ float s_part[32 * 8];
    int b = blockIdx.x, tid = threadIdx.x;
    int r = b >> 6, hc = b & 63;
    float v0 = sc_ws[tid * 4 + r], v1 = sc_ws[(tid + 256) * 4 + r];
    s_red[tid] = fmaxf(v0, v1);
    __syncthreads();
    for (int st = 128; st > 0; st >>= 1) {
        if (tid < st) s_red[tid] = fmaxf(s_red[tid], s_red[tid + st]);
        __syncthreads();
    }
    float mx = s_red[0];
    __syncthreads();
    float e0 = __expf(v0 - mx), e1 = __expf(v1 - mx);
    s_red[tid] = e0 + e1;
    __syncthreads();
    for (int st = 128; st > 0; st >>= 1) {
        if (tid < st) s_red[tid] += s_red[tid + st];
        __syncthreads();
    }
    float rdn = 1.f / s_red[0];
    __syncthreads();
    s_att[tid] = e0 * rdn;
    s_att[tid + 256] = e1 * rdn;
    __syncthreads();
    int hl = tid & 7, tq = tid >> 3;       // 32 t-groups x 16 t
    int h = hc * 8 + hl;
    float acc = 0.f;
    #pragma unroll 4
    for (int t = tq * 16; t < tq * 16 + 16; ++t)
        acc += s_att[t] * rawf(te_raw, isbf, t * 512 + h);
    s_part[tq * 8 + hl] = acc;
    __syncthreads();
    if (tid < 8) {
        float c = 0.f;
        #pragma unroll
        for (int s = 0; s < 32; ++s) c += s_part[s * 8 + tid];
        ctx_ws[r * 512 + hc * 8 + tid] = c;
    }
}

// ---------------- K3 (k_g2): g2 = gate*gg2 + (1-gate)*(ctx @ W2) -------------------------
// 8 blocks x 256 thr; block (r = b>>1, dh = b&1) covers d in [dh*128, +128).
__global__ __launch_bounds__(256) void k_g2(const float* __restrict__ ctx_ws,
                                            const int* __restrict__ adj,
                                            const void* __restrict__ W2_raw,
                                            const void* __restrict__ gg2_raw,
                                            const void* __restrict__ ga_raw,
                                            const unsigned* __restrict__ graw,
                                            float* __restrict__ g2ws) {
    bool isbf = (graw[0] == 0x3F803F80u);
    __shared__ float s_ctx[512];
    __shared__ float s_p[2][128];
    int b = blockIdx.x, tid = threadIdx.x;
    int r = b >> 1, dh = b & 1;
    for (int idx = tid; idx < 512; idx += 256) s_ctx[idx] = ctx_ws[r * 512 + idx];
    __syncthreads();
    int dl = tid & 127, th = tid >> 7;
    int d = dh * 128 + dl;
    float acc = 0.f;
    for (int h = th * 256; h < th * 256 + 256; ++h)
        acc += s_ctx[h] * rawf(W2_raw, isbf, h * 256 + d);
    s_p[th][dl] = acc;
    __syncthreads();
    if (th == 0) {
        float tot = s_p[0][dl] + s_p[1][dl];
        int ar = adj[r];
        float gav = 1.f / (1.f + expf(-rawf(ga_raw, isbf, ar)));
        g2ws[r * 256 + d] = gav * rawf(gg2_raw, isbf, ar * 256 + d) + (1.f - gav) * tot;
    }
}

// ---------------- K4 (k_fplus): fpt[r][kt][c][kk] = e2[r][j]*(WrT @ entity^T) ------------
// R10 structure: 256 UNIFORM blocks (r = b&3, ct = (b>>2)&3, jt = b>>4) x 512 thr.
// e2 in-block wave-parallel, coalesced row loads + butterfly reduce; ct==0
// blocks also write denominator rows c=256..271 for their jt. j = kt*32 + kk.
__global__ __launch_bounds__(512) void k_fplus(const u16* __restrict__ entity,
                                               const u16* __restrict__ wrt,
                                               const float* __restrict__ g2ws,
                                               u16* __restrict__ fpt) {
    int b = blockIdx.x, tid = threadIdx.x;
    int r = b & 3, ct = (b >> 2) & 3, jt = b >> 4;
    int c0 = ct * 64, j0 = jt * 256;
    __shared__ __align__(16) u16 lw[64 * 264];  // 64 c-rows x 256 d (+8 pad) bf16
    __shared__ float sg2[256];
    __shared__ float sE[256];                   // e2 for j0..j0+255
    const u16* wr = wrt + (r * 256 + c0) * 256;
    #pragma unroll
    for (int k = 0; k < 4; ++k) {
        int ci = tid + k * 512; int row = ci >> 5, off = (ci & 31) * 8;
        *(v4i*)(&lw[row * 264 + off]) = *(const v4i*)(wr + row * 256 + off);
    }
    if (tid < 256) sg2[tid] = g2ws[r * 256 + tid];
    __syncthreads();
    int wv = tid >> 6, lane = tid & 63, ln = lane & 15, q = lane >> 4;
    {   // e2: wave wv covers rows j0 + wv*32 .. +31; per row one coalesced 512B load
        float gl0 = sg2[lane * 4 + 0], gl1 = sg2[lane * 4 + 1];
        float gl2 = sg2[lane * 4 + 2], gl3 = sg2[lane * 4 + 3];
        #pragma unroll 4
        for (int i = 0; i < 32; ++i) {
            int row = j0 + wv * 32 + i;
            v2u e4 = *(const v2u*)(entity + row * 256 + lane * 4);
            float s = b2f((u16)(e4.x & 0xFFFFu)) * gl0
                    + b2f((u16)(e4.x >> 16))     * gl1
                    + b2f((u16)(e4.y & 0xFFFFu)) * gl2
                    + b2f((u16)(e4.y >> 16))     * gl3;
            #pragma unroll
            for (int m = 32; m > 0; m >>= 1) s += __shfl_xor(s, m);
            if (lane == 0) sE[wv * 32 + i] = expf(s);
        }
    }
    __syncthreads();
    f32x4 acc[4][2] = {};
    for (int ks = 0; ks < 8; ++ks) {
        bf16x8 afr[4], bfr[2];
        #pragma unroll
        for (int mt = 0; mt < 4; ++mt)
            afr[mt] = *(const bf16x8*)(&lw[(mt * 16 + ln) * 264 + ks * 32 + q * 8]);
        #pragma unroll
        for (int nt = 0; nt < 2; ++nt) {
            int j = j0 + (wv * 2 + nt) * 16 + ln;
            bfr[nt] = *(const bf16x8*)(entity + j * 256 + ks * 32 + q * 8);
        }
        #pragma unroll
        for (int mt = 0; mt < 4; ++mt)
            #pragma unroll
            for (int nt = 0; nt < 2; ++nt)
                acc[mt][nt] = __builtin_amdgcn_mfma_f32_16x16x32_bf16(afr[mt], bfr[nt], acc[mt][nt], 0, 0, 0);
    }
    #pragma unroll
    for (int nt = 0; nt < 2; ++nt) {
        int jl = (wv * 2 + nt) * 16 + ln;
        int j = j0 + jl;
        float e2j = sE[jl];
        int kt = j >> 5, kk = j & 31;
        u16* dst = fpt + (((size_t)(r * 128 + kt)) * 272 << 5);
        #pragma unroll
        for (int mt = 0; mt < 4; ++mt)
            #pragma unroll
            for (int reg = 0; reg < 4; ++reg) {
                int c = c0 + mt * 16 + q * 4 + reg;  // C/D: col=lane&15, row=q*4+reg
                dst[(c << 5) + kk] = f2b(acc[mt][nt][reg] * e2j);
            }
    }
    if (ct == 0) {  // denominator rows for this (r, jt): c==256 carries e2, 257..271 zero
        #pragma unroll
        for (int s = 0; s < 8; ++s) {
            int l = s * 512 + tid;               // 0..4095 = [ktl 8][cl 16][kk 32]
            int kk = l & 31, cl = (l >> 5) & 15, ktl = l >> 9;
            int kt = jt * 8 + ktl;
            fpt[(((size_t)(r * 128 + kt) * 272 + 256 + cl) << 5) + kk] =
                (cl == 0) ? f2b(sE[ktl * 32 + kk]) : (u16)0;
        }
    }
}

// ---------------- K5 (k_big): fused[r][i][c] = (M_r @ FplusT^T) / den --------------------
// grid 256: xcd-pinned r so each XCD's L2 holds one fpt_r (2.2 MB < 4 MB).
// BM=64, BN=272 (16 static N-tiles + den tile on ng==3 waves), BK=32, 8 waves.
// R6 schedule (best): coalesced nontemporal mask staging + dbuf lm/lf,
// ONE barrier per K-step, 4-slot static VGPR rotation.
__global__ __launch_bounds__(512) void k_big(const int* __restrict__ masks,
                                             const u16* __restrict__ fpt,
                                             float* __restrict__ fused) {
    __shared__ __align__(16) u16 lm[2][64 * 40];   // mask tile bf16, 80B rows, dbuf
    __shared__ __align__(16) u16 lf[2][272 * 40];  // fpt tile bf16, 80B rows, dbuf
    __shared__ float lden[64];
    int b = blockIdx.x, tid = threadIdx.x;
    int xcd = b & 7; int r = xcd & 3;
    int it = (b >> 3) + ((xcd >> 2) << 5);
    long i0 = (long)it * 64;
    const int* mbase = masks + ((long)r << 24) + i0 * 4096;
    const u16* fbase = fpt + (size_t)r * 128 * 272 * 32;
    int mrow = tid >> 3, mch = tid & 7;          // mask staging: 8 thr/row, 4 ints each
    int wave = tid >> 6, lane = tid & 63, ln = lane & 15, q = lane >> 4;
    int mg = wave >> 2, ng = wave & 3;

    f32x4 acc[2][4] = {};           // static n-tiles (c = ng*64 .. +63)
    f32x4 accD0 = {}, accD1 = {};   // den tile (c=256..271), ng==3 waves only

    struct Slot { v4i pm, f0, f1, f2; };
    Slot s0, s1, s2, s3;
    auto load_slot = [&](int kt, Slot& s) {
        s.pm = __builtin_nontemporal_load((const v4i*)(mbase + mrow * 4096 + kt * 32 + mch * 4));
        const u16* su = fbase + (size_t)kt * 8704;   // contiguous 272x32 slab
        s.f0 = *(const v4i*)(su + tid * 8);
        s.f1 = *(const v4i*)(su + (tid + 512) * 8);
        if (tid < 64) s.f2 = *(const v4i*)(su + (tid + 1024) * 8);
    };
    auto stage = [&](int par, const Slot& s) {
        {   // int 0/1 -> bf16 (exact: m * 0x3F80); coalesced slab -> lm[par]
            unsigned m0 = (unsigned)s.pm.x * 0x3F80u, m1 = (unsigned)s.pm.y * 0x3F80u;
            unsigned m2 = (unsigned)s.pm.z * 0x3F80u, m3 = (unsigned)s.pm.w * 0x3F80u;
            v2u w; w.x = m0 | (m1 << 16); w.y = m2 | (m3 << 16);
            *(v2u*)(&lm[par][mrow * 40 + mch * 4]) = w;
        }
        u16* dst = &lf[par][0];
        *(v4i*)(dst + (tid >> 2) * 40 + (tid & 3) * 8) = s.f0;
        { int ci = tid + 512; *(v4i*)(dst + (ci >> 2) * 40 + (ci & 3) * 8) = s.f1; }
        if (tid < 64) { int ci = tid + 1024; *(v4i*)(dst + (ci >> 2) * 40 + (ci & 3) * 8) = s.f2; }
    };
    auto step = [&](int k, Slot& sM, Slot& sF) {
        const u16* msrc = &lm[k & 1][0];
        const u16* src  = &lf[k & 1][0];
        bf16x8 a0 = *(const bf16x8*)(msrc + (mg * 32 + ln) * 40 + q * 8);
        bf16x8 a1 = *(const bf16x8*)(msrc + (mg * 32 + 16 + ln) * 40 + q * 8);
        if (k + 1 < 128) stage((k + 1) & 1, sF);
        if (k + 4 < 128) load_slot(k + 4, sM);
        #pragma unroll
        for (int nt = 0; nt < 4; ++nt) {
            bf16x8 bf = *(const bf16x8*)(src + ((ng * 4 + nt) * 16 + ln) * 40 + q * 8);
            acc[0][nt] = __builtin_amdgcn_mfma_f32_16x16x32_bf16(a0, bf, acc[0][nt], 0, 0, 0);
            acc[1][nt] = __builtin_amdgcn_mfma_f32_16x16x32_bf16(a1, bf, acc[1][nt], 0, 0, 0);
        }
        if (ng == 3) {  // wave-uniform branch: denominator tile (c=256..271)
            bf16x8 bf = *(const bf16x8*)(src + (256 + ln) * 40 + q * 8);
            accD0 = __builtin_amdgcn_mfma_f32_16x16x32_bf16(a0, bf, accD0, 0, 0, 0);
            accD1 = __builtin_amdgcn_mfma_f32_16x16x32_bf16(a1, bf, accD1, 0, 0, 0);
        }
        __syncthreads();
    };

    load_slot(0, s0);
    load_slot(1, s1);
    load_slot(2, s2);
    load_slot(3, s3);
    stage(0, s0);
    __syncthreads();
    #pragma unroll 1
    for (int kt = 0; kt < 128; kt += 4) {
        step(kt,     s0, s1);
        step(kt + 1, s1, s2);
        step(kt + 2, s2, s3);
        step(kt + 3, s3, s0);
    }

    if (ng == 3 && ln == 0) {  // den lives in col 0 of the den tile
        #pragma unroll
        for (int reg = 0; reg < 4; ++reg) {
            lden[mg * 32 + q * 4 + reg]      = accD0[reg];
            lden[mg * 32 + 16 + q * 4 + reg] = accD1[reg];
        }
    }
    __syncthreads();
    float* fb = fused + ((long)r * 4096 + i0) * 256;
    #pragma unroll
    for (int mt = 0; mt < 2; ++mt) {
        float rd[4];
        #pragma unroll
        for (int reg = 0; reg < 4; ++reg) rd[reg] = 1.0f / lden[mg * 32 + mt * 16 + q * 4 + reg];
        #pragma unroll
        for (int nt = 0; nt < 4; ++nt) {
            int c = (ng * 4 + nt) * 16 + ln;
            #pragma unroll
            for (int reg = 0; reg < 4; ++reg) {
                int row = mg * 32 + mt * 16 + q * 4 + reg;
                __builtin_nontemporal_store(acc[mt][nt][reg] * rd[reg], fb + row * 256 + c);
            }
        }
    }
}

// ---------------- K6 (k_ln): out = relu(LN(sum_r fused[r])), raw gamma/beta --------------
__global__ __launch_bounds__(256) void k_ln(const float* __restrict__ fused,
                                            const void* __restrict__ gamma_raw,
                                            const void* __restrict__ beta_raw,
                                            const unsigned* __restrict__ graw,
                                            void* __restrict__ outraw) {
    __shared__ float part[8];
    int i = blockIdx.x, o = threadIdx.x;
    bool isbf = (graw[0] == 0x3F803F80u);
    float x = 0.f;
    for (int r = 0; r < 4; ++r)
        x += __builtin_nontemporal_load(fused + ((long)(r << 12) + i) * 256 + o);
    float s = x;
    #pragma unroll
    for (int st = 32; st > 0; st >>= 1) s += __shfl_xor(s, st);
    int w = o >> 6;
    if ((o & 63) == 0) part[w] = s;
    __syncthreads();
    float mu = (part[0] + part[1] + part[2] + part[3]) * (1.f / 256.f);
    float v = x - mu;
    float qv = v * v;
    #pragma unroll
    for (int st = 32; st > 0; st >>= 1) qv += __shfl_xor(qv, st);
    if ((o & 63) == 0) part[4 + w] = qv;
    __syncthreads();
    float var = (part[4] + part[5] + part[6] + part[7]) * (1.f / 256.f);
    float y = v * rsqrtf(var + 1e-5f) * rawf(gamma_raw, isbf, o) + rawf(beta_raw, isbf, o);
    float res = fmaxf(y, 0.f);
    if (isbf) ((u16*)outraw)[i * 256 + o] = f2b(res);
    else      ((float*)outraw)[i * 256 + o] = res;
}

extern "C" void kernel_launch(void* const* d_in, const int* in_sizes, int n_in,
                              void* d_out, int out_size, void* d_ws, size_t ws_size,
                              hipStream_t stream) {
    const int* adj   = (const int*)d_in[2];
    const int* masks = (const int*)d_in[3];
    const unsigned* graw = (const unsigned*)d_in[12];  // ln_gamma raw word (dtype probe)
    char* ws = (char*)d_ws;
    float* g2ws = (float*)(ws + G2_OFF);
    float* scws = (float*)(ws + SC_OFF);
    float* ctxw = (float*)(ws + CTX_OFF);
    u16*   wrt  = (u16*)(ws + WRT_OFF);
    u16*   fpt  = (u16*)(ws + FPT_OFF);
    float* fus  = (float*)(ws + FUSED_OFF);
    u16*   ent  = (u16*)(ws + CAN_OFF);

    // d_in[5] (graph_guids_1) and d_in[10] (W_1) are dead: s1 cancels in softmax.
    k_front<<<416, 512, 0, stream>>>(d_in[0], d_in[1], adj, d_in[4],
                                     d_in[8], d_in[9], graw, ent, scws, wrt);
    k_ctx<<<256, 256, 0, stream>>>(d_in[1], scws, graw, ctxw);
    k_g2<<<8, 256, 0, stream>>>(ctxw, adj, d_in[11], d_in[6], d_in[7], graw, g2ws);
    k_fplus<<<256, 512, 0, stream>>>(ent, wrt, g2ws, fpt);
    k_big<<<256, 512, 0, stream>>>(masks, fpt, fus);
    k_ln<<<4096, 256, 0, stream>>>(fus, d_in[12], d_in[13], graw, d_out);
}